// Round 14
// baseline (242.610 us; speedup 1.0000x reference)
//
#include <hip/hip_runtime.h>
#include <hip/hip_bf16.h>
#include <math.h>

#define NNODES 200000
#define EDGES  65536
#define NSIDES (2*EDGES)        // 131072
#define MD 128
#define TD 100
#define EDIM 128
#define MSGD 256
#define KX 512                  // padded msg K (484 -> 512)
#define KG 384                  // gru combined K (256 agg + 128 mem)
#define NSCAN 782               // ceil(200000/256)
#define GBLK 64                 // k_gru slots per block
#define MSGBLKS (EDGES/32)      // 2048 msg blocks
#define CPBLKS  6250            // copy blocks: 6.4M float4 / (512 thr * 2)
#define PACKBLKS 1152           // weight-pack blocks
#define TSBLKS   196            // ts-copy blocks (50000 float4 / 256)

typedef __attribute__((ext_vector_type(8))) short bf16x8;
typedef __attribute__((ext_vector_type(4))) float f32x4;

// ---- workspace layout (bytes) ----
#define O_COUNTS    0u           // int[200000] -> becomes cursor after scan3
#define O_NUMUPD    800000u      // int
#define O_BSUMC     800004u      // int[782]
#define O_BSUMF     803132u      // int[782]
#define O_UPDLIST   806272u      // int[131073]
#define O_SEGSTART  1330592u     // int[131073]
#define O_CNTLIST   1854912u     // int[131072]
#define O_BMSG      2379200u     // short[16*16*64*8] = 262144 B
#define O_BG        2641344u     // short[12*24*64*8] = 294912 B
#define O_BH        2936256u     // short[4*8*64*8]   = 32768 B
#define O_MSGBUF    2969088u     // ushort[131072*256] = 67108864 B
#define O_UPDFLAG   (2969088u + 67108864u)   // uchar[200000]
#define WS_NEEDED   (2969088ull + 67108864ull + 200000ull)

__device__ __forceinline__ short f2bf(float v) {            // RNE f32->bf16 (verified)
    unsigned x = __float_as_uint(v);
    unsigned r = (x + 0x7fffu + ((x >> 16) & 1u)) >> 16;
    return (short)r;
}
__device__ __forceinline__ unsigned pk2bf(float a, float b) {    // lo=a, hi=b (pure bit ops, verified r11)
    unsigned xa = __float_as_uint(a);
    unsigned xb = __float_as_uint(b);
    unsigned ra = (xa + 0x7fffu + ((xa >> 16) & 1u)) >> 16;
    unsigned rb = (xb + 0x7fffu + ((xb >> 16) & 1u)) & 0xffff0000u;
    return ra | rb;
}
__device__ __forceinline__ float bflo(unsigned u) { return __uint_as_float(u << 16); }
__device__ __forceinline__ float bfhi(unsigned u) { return __uint_as_float(u & 0xffff0000u); }
__device__ __forceinline__ float bf2f(unsigned short u) {
    return __uint_as_float(((unsigned)u) << 16);
}
__device__ __forceinline__ f32x4 mfma16(bf16x8 a, bf16x8 b, f32x4 c) {
    return __builtin_amdgcn_mfma_f32_16x16x32_bf16(a, b, c, 0, 0, 0);
}

// pack weights into MFMA-fragment-linear bf16; tail blocks copy last -> out_ts.
// A-frag: lane l holds A[row=l&15][k=(l>>4)*8+j]; B-frag: lane l holds B[k=(l>>4)*8+j][col=l&15]
__global__ __launch_bounds__(256) void k_pack(const float* __restrict__ wmsg,
                                              const float* __restrict__ wih,
                                              const float* __restrict__ whh,
                                              short* __restrict__ bmsgp,
                                              short* __restrict__ bgp,
                                              short* __restrict__ bhp,
                                              const float* __restrict__ last,
                                              float* __restrict__ out_ts) {
    if (blockIdx.x >= PACKBLKS) {                      // ts-copy path
        int i = (blockIdx.x - PACKBLKS) * 256 + threadIdx.x;
        if (i < NNODES / 4) ((float4*)out_ts)[i] = ((const float4*)last)[i];
        return;
    }
    const int NM = 16 * 16 * 64 * 8;   // K=512, N=256
    const int NG = 12 * 24 * 64 * 8;   // K=384, N=384
    const int NH = 4 * 8 * 64 * 8;     // K=128, N=128 (n-gate of W_hh)
    int idx = blockIdx.x * 256 + threadIdx.x;
    if (idx < NM) {
        int j = idx & 7, l = (idx >> 3) & 63, nf = (idx >> 9) & 15, ks = idx >> 13;
        int n = nf * 16 + (l & 15);
        int k = ks * 32 + ((l >> 4) << 3) + j;
        bmsgp[idx] = f2bf(k < 484 ? wmsg[n * 484 + k] : 0.f);
    } else if (idx < NM + NG) {
        int i = idx - NM;
        int j = i & 7, l = (i >> 3) & 63, rest = i >> 9;
        int nf = rest % 24, ks = rest / 24;
        int n = nf * 16 + (l & 15);
        int k = ks * 32 + ((l >> 4) << 3) + j;
        float v = (k < 256) ? wih[n * 256 + k] : whh[n * 128 + (k - 256)];
        bgp[i] = f2bf(v);
    } else if (idx < NM + NG + NH) {
        int i = idx - NM - NG;
        int j = i & 7, l = (i >> 3) & 63, rest = i >> 9;
        int nf = rest & 7, ks = rest >> 3;
        int n = 256 + nf * 16 + (l & 15);
        int k = ks * 32 + ((l >> 4) << 3) + j;
        bhp[i] = f2bf(whh[n * 128 + k]);
    }
}

__global__ __launch_bounds__(256) void k_edges(const int* __restrict__ src, const int* __restrict__ dst,
                                               const float* __restrict__ ts,
                                               int* __restrict__ counts, float* __restrict__ out_ts) {
    int e = blockIdx.x * blockDim.x + threadIdx.x;
    if (e >= EDGES) return;
    int s = src[e], d = dst[e];
    unsigned tb = __float_as_uint(ts[e]);   // ts >= 0 -> uint order == float order
    atomicAdd(&counts[s], 1);
    atomicAdd(&counts[d], 1);
    atomicMax((unsigned*)&out_ts[s], tb);
    atomicMax((unsigned*)&out_ts[d], tb);
}

__global__ __launch_bounds__(256) void k_scan1(const int* __restrict__ counts,
                                               int* __restrict__ bsumC, int* __restrict__ bsumF) {
    __shared__ int sC[256], sF[256];
    int t = threadIdx.x, i = blockIdx.x * 256 + t;
    int c = (i < NNODES) ? counts[i] : 0;
    sC[t] = c; sF[t] = (c > 0) ? 1 : 0;
    __syncthreads();
    for (int off = 128; off > 0; off >>= 1) {
        if (t < off) { sC[t] += sC[t + off]; sF[t] += sF[t + off]; }
        __syncthreads();
    }
    if (t == 0) { bsumC[blockIdx.x] = sC[0]; bsumF[blockIdx.x] = sF[0]; }
}

__global__ __launch_bounds__(1024) void k_scan2(int* __restrict__ bsumC, int* __restrict__ bsumF,
                                                int* __restrict__ numupd) {
    __shared__ int sC[1024], sF[1024];
    int t = threadIdx.x;
    int c = (t < NSCAN) ? bsumC[t] : 0;
    int f = (t < NSCAN) ? bsumF[t] : 0;
    sC[t] = c; sF[t] = f;
    __syncthreads();
    for (int off = 1; off < 1024; off <<= 1) {
        int vc = (t >= off) ? sC[t - off] : 0;
        int vf = (t >= off) ? sF[t - off] : 0;
        __syncthreads();
        sC[t] += vc; sF[t] += vf;
        __syncthreads();
    }
    if (t < NSCAN) { bsumC[t] = sC[t] - c; bsumF[t] = sF[t] - f; }  // exclusive
    if (t == 0) numupd[0] = sF[1023];
}

__global__ __launch_bounds__(256) void k_scan3(int* __restrict__ counts,   // in: counts, out: cursor
                                               const int* __restrict__ bsumC, const int* __restrict__ bsumF,
                                               int* __restrict__ updlist, int* __restrict__ segstart,
                                               int* __restrict__ cntlist, const int* __restrict__ numupd,
                                               unsigned char* __restrict__ updflag) {
    __shared__ int sC[256], sF[256];
    int t = threadIdx.x, b = blockIdx.x, i = b * 256 + t;
    int c = (i < NNODES) ? counts[i] : 0;
    int fl = (c > 0) ? 1 : 0;
    sC[t] = c; sF[t] = fl;
    __syncthreads();
    for (int off = 1; off < 256; off <<= 1) {
        int vc = (t >= off) ? sC[t - off] : 0;
        int vf = (t >= off) ? sF[t - off] : 0;
        __syncthreads();
        sC[t] += vc; sF[t] += vf;
        __syncthreads();
    }
    if (i < NNODES) {
        int segC = bsumC[b] + sC[t] - c;
        int rank = bsumF[b] + sF[t] - fl;
        if (fl) {
            updlist[rank]  = i;
            segstart[rank] = segC;
            cntlist[rank]  = c;
        }
        updflag[i] = (unsigned char)fl;
        counts[i] = segC;                              // becomes cursor
        if (i == NNODES - 1) segstart[numupd[0]] = segC + c;   // sentinel = 131072
    }
}

// message GEMM (blocks < MSGBLKS): 32 EDGES (64 rows)/block, 512 threads, single-phase.
// Tail blocks: copy non-updated mem rows to out (overlaps with msg compute).
__global__ __launch_bounds__(512) void k_msg(const int* __restrict__ src, const int* __restrict__ dst,
                                             const float* __restrict__ ts, const float* __restrict__ ef,
                                             const float* __restrict__ mem, const float* __restrict__ last,
                                             const float* __restrict__ bfq, const float* __restrict__ ph,
                                             const short* __restrict__ Bp, const float* __restrict__ bmsg,
                                             int* __restrict__ cursor, unsigned short* __restrict__ msgbuf,
                                             const unsigned char* __restrict__ updflag,
                                             float* __restrict__ outmem) {
    __shared__ short As[64 * KX];                      // 64 KiB
    __shared__ int srcS[32], dstS[32], posS[64];
    __shared__ float dtS[64];
    const int t = threadIdx.x;

    if (blockIdx.x >= MSGBLKS) {                       // copy path (non-updated rows)
        size_t base = (size_t)(blockIdx.x - MSGBLKS) * 1024 + t * 2;
        #pragma unroll
        for (int i = 0; i < 2; ++i) {
            size_t idx = base + i;                     // one float4
            int node = (int)(idx >> 5);
            if (!updflag[node]) ((float4*)outmem)[idx] = ((const float4*)mem)[idx];
        }
        return;
    }
    const int e0 = blockIdx.x * 32;

    // metadata: 64 threads, one per row (side). row 2e+0: self=src; row 2e+1: self=dst.
    if (t < 64) {
        int el = t >> 1, which = t & 1;
        int e = e0 + el;
        int s = src[e], d = dst[e];
        int self = which ? d : s;
        if (which == 0) { srcS[el] = s; dstS[el] = d; }
        dtS[t]  = ts[e] - last[self];
        posS[t] = atomicAdd(&cursor[self], 1);
    }
    __syncthreads();

    const int c4 = t & 31;          // float4 column within a 128-float row
    const int rg = t >> 5;          // group 0..15
    // mem gather: 64 node-rows (32 edges x {src,dst}), each written to BOTH x-rows
    #pragma unroll
    for (int i = 0; i < 4; ++i) {
        int nr = rg + i * 16;       // 0..63
        int el = nr >> 1, which = nr & 1;       // which: 0=src row, 1=dst row
        int node = which ? dstS[el] : srcS[el];
        float4 v = *(const float4*)&mem[(size_t)node * MD + c4 * 4];
        uint2 b = make_uint2(pk2bf(v.x, v.y), pk2bf(v.z, v.w));
        int rA = 2 * el, rB = 2 * el + 1;
        int swA = (rA & 7) << 3, swB = (rB & 7) << 3;
        int c16 = c4 * 4;
        if (which == 0) {           // src memory: self for row A (k=128), other for row B (k=0)
            *(uint2*)&As[rA * KX + ((128 + c16) ^ swA)] = b;
            *(uint2*)&As[rB * KX + ((0   + c16) ^ swB)] = b;
        } else {                    // dst memory: other for row A (k=0), self for row B (k=128)
            *(uint2*)&As[rA * KX + ((0   + c16) ^ swA)] = b;
            *(uint2*)&As[rB * KX + ((128 + c16) ^ swB)] = b;
        }
    }
    // edge feats: k = 356..483, written to both rows
    #pragma unroll
    for (int i = 0; i < 2; ++i) {
        int el = rg + i * 16;       // 0..31
        float4 v = *(const float4*)&ef[(size_t)(e0 + el) * EDIM + c4 * 4];
        uint2 b = make_uint2(pk2bf(v.x, v.y), pk2bf(v.z, v.w));
        int k = 356 + c4 * 4;       // %8 in {4,0}: stays inside one 8-short granule
        int rA = 2 * el, rB = 2 * el + 1;
        *(uint2*)&As[rA * KX + (k ^ ((rA & 7) << 3))] = b;
        *(uint2*)&As[rB * KX + (k ^ ((rB & 7) << 3))] = b;
    }
    // time encoding: k = 256..355 (per-row dt); 8 j-groups of 13
    {
        int s = t & 63, jg = t >> 6;
        float dt = dtS[s];
        int sw = (s & 7) << 3;
        int j1 = min(jg * 13 + 13, TD);
        for (int j = jg * 13; j < j1; ++j) {
            float v = __cosf(fmaf(dt, bfq[j], ph[j]));
            As[s * KX + ((256 + j) ^ sw)] = f2bf(v);
        }
    }
    // zero pad: k = 484..511 (64 rows x 7 short4)
    if (t < 448) {
        int s = t / 7, p = t % 7;
        int sw = (s & 7) << 3;
        int k = 484 + p * 4;
        *(short4*)&As[s * KX + (k ^ sw)] = make_short4(0, 0, 0, 0);
    }
    __syncthreads();

    const int w = t >> 6, l = t & 63, lc = l & 15, lq = l >> 4;
    f32x4 acc[4][2];                 // [row-tile][f]
    #pragma unroll
    for (int i = 0; i < 4; ++i)
        #pragma unroll
        for (int j = 0; j < 2; ++j) acc[i][j] = (f32x4){0.f, 0.f, 0.f, 0.f};

    const int rsw = (lc & 7) << 3;
    for (int ks = 0; ks < 16; ++ks) {
        bf16x8 a[4];
        #pragma unroll
        for (int rt = 0; rt < 4; ++rt)
            a[rt] = *(const bf16x8*)&As[(rt * 16 + lc) * KX + ((ks * 32 + (lq << 3)) ^ rsw)];
        #pragma unroll
        for (int f = 0; f < 2; ++f) {
            bf16x8 b = *(const bf16x8*)(Bp + (size_t)(ks * 16 + w * 2 + f) * 512 + l * 8);
            #pragma unroll
            for (int rt = 0; rt < 4; ++rt)
                acc[rt][f] = mfma16(a[rt], b, acc[rt][f]);
        }
    }

    float bb[2];
    #pragma unroll
    for (int f = 0; f < 2; ++f) bb[f] = bmsg[w * 32 + f * 16 + lc];
    #pragma unroll
    for (int rt = 0; rt < 4; ++rt) {
        #pragma unroll
        for (int jj = 0; jj < 4; ++jj) {
            int srow = rt * 16 + lq * 4 + jj;
            unsigned short* orow = msgbuf + (size_t)posS[srow] * MSGD;
            #pragma unroll
            for (int f = 0; f < 2; ++f) {
                int c = w * 32 + f * 16 + lc;
                float v = fmaxf(acc[rt][f][jj] + bb[f], 0.f);
                orow[c] = (unsigned short)f2bf(v);
            }
        }
    }
}

// GRU: 64 consecutive updated nodes/block, 512 threads (8 waves), single-phase (48 KiB LDS).
// mem staging issued FIRST, one barrier, full K=384 MFMA; epilogue: mv register-staged
// BEFORE the overlay write (race-free), then f32 LDS-transpose + coalesced row stores.
__global__ __launch_bounds__(512) void k_gru(const int* __restrict__ updlist, const int* __restrict__ segstart,
                                             const int* __restrict__ cntlist, const int* __restrict__ numupd,
                                             const unsigned short* __restrict__ msgbuf,
                                             const float* __restrict__ mem,
                                             const short* __restrict__ Bg, const short* __restrict__ Bh,
                                             const float* __restrict__ bih, const float* __restrict__ bhh,
                                             float* __restrict__ outmem) {
    __shared__ short Ag[GBLK * KG];                    // 48 KiB; epilogue overlays f32[64][128] on first 32 KiB
    __shared__ int sb[GBLK + 1];
    __shared__ int nodesh[GBLK];
    __shared__ float invh[GBLK];
    const int nu = *numupd;
    const int slot0 = blockIdx.x * GBLK;
    if (slot0 >= nu) return;
    const int t = threadIdx.x;
    if (t < GBLK + 1) sb[t] = segstart[min(slot0 + t, nu)];
    if (t < GBLK) {
        int slot = slot0 + t;
        if (slot < nu) { nodesh[t] = updlist[slot]; invh[t] = 1.f / (float)cntlist[slot]; }
        else           { nodesh[t] = -1;            invh[t] = 0.f; }
    }
    __syncthreads();

    // mem rows -> Ag[s][256..384)   (issued first: overlaps the seg-sum stream below)
    {
        const int c4 = t & 31, rg = t >> 5;
        #pragma unroll
        for (int i = 0; i < 4; ++i) {
            int s = rg + i * 16;
            int node = nodesh[s];
            float4 v = make_float4(0.f, 0.f, 0.f, 0.f);
            if (node >= 0) v = *(const float4*)&mem[(size_t)node * MD + c4 * 4];
            int sw = (s & 7) << 3;
            *(uint2*)&Ag[s * KG + ((256 + c4 * 4) ^ sw)] =
                make_uint2(pk2bf(v.x, v.y), pk2bf(v.z, v.w));
        }
    }
    // f32 register segment-sum: 8 threads per slot, 32 cols each (contiguous span reads)
    {
        const int g = t >> 3, q = t & 7;
        float acc[32];
        #pragma unroll
        for (int m = 0; m < 32; ++m) acc[m] = 0.f;
        const int j0 = sb[g], j1 = sb[g + 1];
        for (int j = j0; j < j1; ++j) {
            const unsigned short* rp = msgbuf + (size_t)j * MSGD + q * 32;
            #pragma unroll
            for (int h = 0; h < 4; ++h) {
                uint4 u = *(const uint4*)(rp + h * 8);
                acc[h*8+0] += bflo(u.x); acc[h*8+1] += bfhi(u.x);
                acc[h*8+2] += bflo(u.y); acc[h*8+3] += bfhi(u.y);
                acc[h*8+4] += bflo(u.z); acc[h*8+5] += bfhi(u.z);
                acc[h*8+6] += bflo(u.w); acc[h*8+7] += bfhi(u.w);
            }
        }
        const float inv = invh[g];
        const int sw = (g & 7) << 3;
        #pragma unroll
        for (int h = 0; h < 4; ++h) {
            uint4 o;
            o.x = pk2bf(acc[h*8+0] * inv, acc[h*8+1] * inv);
            o.y = pk2bf(acc[h*8+2] * inv, acc[h*8+3] * inv);
            o.z = pk2bf(acc[h*8+4] * inv, acc[h*8+5] * inv);
            o.w = pk2bf(acc[h*8+6] * inv, acc[h*8+7] * inv);
            *(uint4*)&Ag[g * KG + ((q * 32 + h * 8) ^ sw)] = o;
        }
    }
    __syncthreads();

    // MFMA: wave w -> gate col group nf = g*8+w (g<3), H col group nf = w; all 4 row-tiles.
    const int w = t >> 6, l = t & 63, lc = l & 15, lq = l >> 4;
    f32x4 accS[4][3], accH[4];
    #pragma unroll
    for (int rt = 0; rt < 4; ++rt) {
        #pragma unroll
        for (int g = 0; g < 3; ++g) accS[rt][g] = (f32x4){0.f, 0.f, 0.f, 0.f};
        accH[rt] = (f32x4){0.f, 0.f, 0.f, 0.f};
    }

    const int rsw = (lc & 7) << 3;
    for (int ks = 0; ks < 12; ++ks) {
        bf16x8 a[4];
        #pragma unroll
        for (int rt = 0; rt < 4; ++rt)
            a[rt] = *(const bf16x8*)&Ag[(rt * 16 + lc) * KG + ((ks * 32 + (lq << 3)) ^ rsw)];
        #pragma unroll
        for (int g = 0; g < 3; ++g) {
            bf16x8 b = *(const bf16x8*)(Bg + (size_t)(ks * 24 + g * 8 + w) * 512 + l * 8);
            #pragma unroll
            for (int rt = 0; rt < 4; ++rt)
                accS[rt][g] = mfma16(a[rt], b, accS[rt][g]);
        }
        if (ks >= 8) {
            bf16x8 b = *(const bf16x8*)(Bh + (size_t)((ks - 8) * 8 + w) * 512 + l * 8);
            #pragma unroll
            for (int rt = 0; rt < 4; ++rt)
                accH[rt] = mfma16(a[rt], b, accH[rt]);
        }
    }

    // register-stage mv (reads of Ag mem region) BEFORE any overlay write
    float mvr[4][4];
    {
        int d = w * 16 + lc;
        #pragma unroll
        for (int rt = 0; rt < 4; ++rt)
            #pragma unroll
            for (int jj = 0; jj < 4; ++jj) {
                int srow = rt * 16 + lq * 4 + jj;
                int sw = (srow & 7) << 3;
                mvr[rt][jj] = bf2f((unsigned short)Ag[srow * KG + ((256 + d) ^ sw)]);
            }
    }
    __syncthreads();                                   // ALL reads of Ag complete

    // epilogue: compute gate math, write f32 outputs to overlay (first 32 KiB of Ag)
    {
        float* O = (float*)Ag;
        int d = w * 16 + lc;
        float br  = bih[d] + bhh[d];
        float bz  = bih[MD + d] + bhh[MD + d];
        float bin = bih[2 * MD + d];
        float bhn = bhh[2 * MD + d];
        #pragma unroll
        for (int rt = 0; rt < 4; ++rt) {
            #pragma unroll
            for (int jj = 0; jj < 4; ++jj) {
                int srow = rt * 16 + lq * 4 + jj;
                float S_r = accS[rt][0][jj] + br;
                float S_z = accS[rt][1][jj] + bz;
                float hn  = accH[rt][jj] + bhn;
                float in_ = accS[rt][2][jj] - accH[rt][jj] + bin;
                float rr = 1.f / (1.f + __expf(-S_r));
                float zz = 1.f / (1.f + __expf(-S_z));
                float x  = fminf(fmaxf(in_ + rr * hn, -15.f), 15.f);
                float ex = __expf(-2.f * x);
                float nn = (1.f - ex) / (1.f + ex);
                float outv = (1.f - zz) * nn + zz * mvr[rt][jj];
                O[srow * 128 + (d ^ ((srow & 7) << 2))] = outv;
            }
        }
    }
    __syncthreads();

    // coalesced store: 8 threads/row, 4 float4 each
    {
        const float* O = (const float*)Ag;
        int row = t >> 3, q = t & 7;
        int node = nodesh[row];
        if (node >= 0) {
            float* orow = outmem + (size_t)node * MD;
            int sw2 = (row & 7) << 2;
            #pragma unroll
            for (int i = 0; i < 4; ++i) {
                int c0 = (q * 4 + i) * 4;
                float4 v = *(const float4*)&O[row * 128 + (c0 ^ sw2)];
                *(float4*)&orow[c0] = v;
            }
        }
    }
}

extern "C" void kernel_launch(void* const* d_in, const int* in_sizes, int n_in,
                              void* d_out, int out_size, void* d_ws, size_t ws_size,
                              hipStream_t stream) {
    const int*   src  = (const int*)d_in[0];
    const int*   dst  = (const int*)d_in[1];
    const float* ts   = (const float*)d_in[2];
    const float* ef   = (const float*)d_in[3];
    const float* mem  = (const float*)d_in[4];
    const float* last = (const float*)d_in[5];
    const float* bfq  = (const float*)d_in[6];
    const float* ph   = (const float*)d_in[7];
    const float* wmsg = (const float*)d_in[8];
    const float* bmsg = (const float*)d_in[9];
    const float* wih  = (const float*)d_in[10];
    const float* whh  = (const float*)d_in[11];
    const float* bih  = (const float*)d_in[12];
    const float* bhh  = (const float*)d_in[13];
    float* out = (float*)d_out;
    char* ws = (char*)d_ws;

    if (ws_size < WS_NEEDED) return;

    int* counts   = (int*)(ws + O_COUNTS);     // -> cursor after k_scan3
    int* numupd   = (int*)(ws + O_NUMUPD);
    int* bsumC    = (int*)(ws + O_BSUMC);
    int* bsumF    = (int*)(ws + O_BSUMF);
    int* updlist  = (int*)(ws + O_UPDLIST);
    int* segstart = (int*)(ws + O_SEGSTART);
    int* cntlist  = (int*)(ws + O_CNTLIST);
    short* bmsgp  = (short*)(ws + O_BMSG);
    short* bgp    = (short*)(ws + O_BG);
    short* bhp    = (short*)(ws + O_BH);
    unsigned short* msgbuf = (unsigned short*)(ws + O_MSGBUF);
    unsigned char*  updflag = (unsigned char*)(ws + O_UPDFLAG);
    float* out_ts = out + (size_t)NNODES * MD;

    hipMemsetAsync(ws + O_COUNTS, 0, 800004, stream);   // counts + numupd

    k_pack <<<PACKBLKS + TSBLKS, 256, 0, stream>>>(wmsg, wih, whh, bmsgp, bgp, bhp, last, out_ts);
    k_edges<<<EDGES / 256, 256, 0, stream>>>(src, dst, ts, counts, out_ts);
    k_scan1<<<NSCAN, 256, 0, stream>>>(counts, bsumC, bsumF);
    k_scan2<<<1, 1024, 0, stream>>>(bsumC, bsumF, numupd);
    k_scan3<<<NSCAN, 256, 0, stream>>>(counts, bsumC, bsumF, updlist, segstart, cntlist, numupd, updflag);
    k_msg  <<<MSGBLKS + CPBLKS, 512, 0, stream>>>(src, dst, ts, ef, mem, last, bfq, ph, bmsgp, bmsg,
                                                  counts, msgbuf, updflag, out);
    k_gru  <<<NSIDES / GBLK, 512, 0, stream>>>(updlist, segstart, cntlist, numupd, msgbuf, mem, bgp, bhp, bih, bhh, out);
}

// Round 15
// 229.714 us; speedup vs baseline: 1.0561x; 1.0561x over previous
//
#include <hip/hip_runtime.h>
#include <hip/hip_bf16.h>
#include <math.h>

#define NNODES 200000
#define EDGES  65536
#define NSIDES (2*EDGES)        // 131072
#define MD 128
#define TD 100
#define EDIM 128
#define MSGD 256
#define KX 512                  // padded msg K (484 -> 512)
#define KG 384                  // gru combined K (256 agg + 128 mem)
#define NSCAN 782               // ceil(200000/256)
#define GBLK 64                 // k_gru slots per block

typedef __attribute__((ext_vector_type(8))) short bf16x8;
typedef __attribute__((ext_vector_type(4))) float f32x4;

// ---- workspace layout (bytes) ----
#define O_COUNTS    0u           // int[200000] -> becomes cursor after scan3
#define O_NUMUPD    800000u      // int
#define O_BSUMC     800004u      // int[782]
#define O_BSUMF     803132u      // int[782]
#define O_UPDLIST   806272u      // int[131073]
#define O_SEGSTART  1330592u     // int[131073]
#define O_CNTLIST   1854912u     // int[131072]
#define O_BMSG      2379200u     // short[16*16*64*8] = 262144 B
#define O_BG        2641344u     // short[12*24*64*8] = 294912 B
#define O_BH        2936256u     // short[4*8*64*8]   = 32768 B
#define O_MSGBUF    2969088u     // ushort[131072*256] = 67108864 B
#define O_UPDFLAG   (2969088u + 67108864u)   // uchar[200000]
#define WS_NEEDED   (2969088ull + 67108864ull + 200000ull)

__device__ __forceinline__ short f2bf(float v) {            // RNE f32->bf16 (verified)
    unsigned x = __float_as_uint(v);
    unsigned r = (x + 0x7fffu + ((x >> 16) & 1u)) >> 16;
    return (short)r;
}
__device__ __forceinline__ unsigned pk2bf(float a, float b) {    // lo=a, hi=b (pure bit ops, verified r11)
    unsigned xa = __float_as_uint(a);
    unsigned xb = __float_as_uint(b);
    unsigned ra = (xa + 0x7fffu + ((xa >> 16) & 1u)) >> 16;
    unsigned rb = (xb + 0x7fffu + ((xb >> 16) & 1u)) & 0xffff0000u;
    return ra | rb;
}
__device__ __forceinline__ float bflo(unsigned u) { return __uint_as_float(u << 16); }
__device__ __forceinline__ float bfhi(unsigned u) { return __uint_as_float(u & 0xffff0000u); }
__device__ __forceinline__ float bf2f(unsigned short u) {
    return __uint_as_float(((unsigned)u) << 16);
}
__device__ __forceinline__ f32x4 mfma16(bf16x8 a, bf16x8 b, f32x4 c) {
    return __builtin_amdgcn_mfma_f32_16x16x32_bf16(a, b, c, 0, 0, 0);
}

// ts copy: out_ts = last (must run before k_edges' atomicMax)
__global__ __launch_bounds__(256) void k_copy_ts(const float* __restrict__ last,
                                                 float* __restrict__ out_ts) {
    int i = blockIdx.x * 256 + threadIdx.x;
    if (i < NNODES / 4) ((float4*)out_ts)[i] = ((const float4*)last)[i];
}

// mem copy for NON-updated rows only (runs after scan3; updated rows written by k_gru)
__global__ __launch_bounds__(256) void k_copy_mem(const float* __restrict__ mem,
                                                  const unsigned char* __restrict__ updflag,
                                                  float* __restrict__ out) {
    size_t idx = (size_t)blockIdx.x * 256 + threadIdx.x;   // one float4 each
    if (idx >= (size_t)NNODES * 32) return;
    int node = (int)(idx >> 5);
    if (updflag[node]) return;
    ((float4*)out)[idx] = ((const float4*)mem)[idx];
}

// pack weights into MFMA-fragment-linear bf16
// A-frag: lane l holds A[row=l&15][k=(l>>4)*8+j]; B-frag: lane l holds B[k=(l>>4)*8+j][col=l&15]
__global__ __launch_bounds__(256) void k_pack(const float* __restrict__ wmsg,
                                              const float* __restrict__ wih,
                                              const float* __restrict__ whh,
                                              short* __restrict__ bmsgp,
                                              short* __restrict__ bgp,
                                              short* __restrict__ bhp) {
    const int NM = 16 * 16 * 64 * 8;   // K=512, N=256
    const int NG = 12 * 24 * 64 * 8;   // K=384, N=384
    const int NH = 4 * 8 * 64 * 8;     // K=128, N=128 (n-gate of W_hh)
    int idx = blockIdx.x * 256 + threadIdx.x;
    if (idx < NM) {
        int j = idx & 7, l = (idx >> 3) & 63, nf = (idx >> 9) & 15, ks = idx >> 13;
        int n = nf * 16 + (l & 15);
        int k = ks * 32 + ((l >> 4) << 3) + j;
        bmsgp[idx] = f2bf(k < 484 ? wmsg[n * 484 + k] : 0.f);
    } else if (idx < NM + NG) {
        int i = idx - NM;
        int j = i & 7, l = (i >> 3) & 63, rest = i >> 9;
        int nf = rest % 24, ks = rest / 24;
        int n = nf * 16 + (l & 15);
        int k = ks * 32 + ((l >> 4) << 3) + j;
        float v = (k < 256) ? wih[n * 256 + k] : whh[n * 128 + (k - 256)];
        bgp[i] = f2bf(v);
    } else if (idx < NM + NG + NH) {
        int i = idx - NM - NG;
        int j = i & 7, l = (i >> 3) & 63, rest = i >> 9;
        int nf = rest & 7, ks = rest >> 3;
        int n = 256 + nf * 16 + (l & 15);
        int k = ks * 32 + ((l >> 4) << 3) + j;
        bhp[i] = f2bf(whh[n * 128 + k]);
    }
}

__global__ __launch_bounds__(256) void k_edges(const int* __restrict__ src, const int* __restrict__ dst,
                                               const float* __restrict__ ts,
                                               int* __restrict__ counts, float* __restrict__ out_ts) {
    int e = blockIdx.x * blockDim.x + threadIdx.x;
    if (e >= EDGES) return;
    int s = src[e], d = dst[e];
    unsigned tb = __float_as_uint(ts[e]);   // ts >= 0 -> uint order == float order
    atomicAdd(&counts[s], 1);
    atomicAdd(&counts[d], 1);
    atomicMax((unsigned*)&out_ts[s], tb);
    atomicMax((unsigned*)&out_ts[d], tb);
}

__global__ __launch_bounds__(256) void k_scan1(const int* __restrict__ counts,
                                               int* __restrict__ bsumC, int* __restrict__ bsumF) {
    __shared__ int sC[256], sF[256];
    int t = threadIdx.x, i = blockIdx.x * 256 + t;
    int c = (i < NNODES) ? counts[i] : 0;
    sC[t] = c; sF[t] = (c > 0) ? 1 : 0;
    __syncthreads();
    for (int off = 128; off > 0; off >>= 1) {
        if (t < off) { sC[t] += sC[t + off]; sF[t] += sF[t + off]; }
        __syncthreads();
    }
    if (t == 0) { bsumC[blockIdx.x] = sC[0]; bsumF[blockIdx.x] = sF[0]; }
}

__global__ __launch_bounds__(1024) void k_scan2(int* __restrict__ bsumC, int* __restrict__ bsumF,
                                                int* __restrict__ numupd) {
    __shared__ int sC[1024], sF[1024];
    int t = threadIdx.x;
    int c = (t < NSCAN) ? bsumC[t] : 0;
    int f = (t < NSCAN) ? bsumF[t] : 0;
    sC[t] = c; sF[t] = f;
    __syncthreads();
    for (int off = 1; off < 1024; off <<= 1) {
        int vc = (t >= off) ? sC[t - off] : 0;
        int vf = (t >= off) ? sF[t - off] : 0;
        __syncthreads();
        sC[t] += vc; sF[t] += vf;
        __syncthreads();
    }
    if (t < NSCAN) { bsumC[t] = sC[t] - c; bsumF[t] = sF[t] - f; }  // exclusive
    if (t == 0) numupd[0] = sF[1023];
}

__global__ __launch_bounds__(256) void k_scan3(int* __restrict__ counts,   // in: counts, out: cursor
                                               const int* __restrict__ bsumC, const int* __restrict__ bsumF,
                                               int* __restrict__ updlist, int* __restrict__ segstart,
                                               int* __restrict__ cntlist, const int* __restrict__ numupd,
                                               unsigned char* __restrict__ updflag) {
    __shared__ int sC[256], sF[256];
    int t = threadIdx.x, b = blockIdx.x, i = b * 256 + t;
    int c = (i < NNODES) ? counts[i] : 0;
    int fl = (c > 0) ? 1 : 0;
    sC[t] = c; sF[t] = fl;
    __syncthreads();
    for (int off = 1; off < 256; off <<= 1) {
        int vc = (t >= off) ? sC[t - off] : 0;
        int vf = (t >= off) ? sF[t - off] : 0;
        __syncthreads();
        sC[t] += vc; sF[t] += vf;
        __syncthreads();
    }
    if (i < NNODES) {
        int segC = bsumC[b] + sC[t] - c;
        int rank = bsumF[b] + sF[t] - fl;
        if (fl) {
            updlist[rank]  = i;
            segstart[rank] = segC;
            cntlist[rank]  = c;
        }
        updflag[i] = (unsigned char)fl;
        counts[i] = segC;                              // becomes cursor
        if (i == NNODES - 1) segstart[numupd[0]] = segC + c;   // sentinel = 131072
    }
}

// message GEMM: 32 EDGES (64 rows) per block, 512 threads (8 waves), single-phase (64 KiB LDS).
// Each wave owns 2 nf (32 cols) over all 64 rows -> every B-frag loaded once per block.
__global__ __launch_bounds__(512) void k_msg(const int* __restrict__ src, const int* __restrict__ dst,
                                             const float* __restrict__ ts, const float* __restrict__ ef,
                                             const float* __restrict__ mem, const float* __restrict__ last,
                                             const float* __restrict__ bfq, const float* __restrict__ ph,
                                             const short* __restrict__ Bp, const float* __restrict__ bmsg,
                                             int* __restrict__ cursor, unsigned short* __restrict__ msgbuf) {
    __shared__ short As[64 * KX];                      // 64 KiB
    __shared__ int srcS[32], dstS[32], posS[64];
    __shared__ float dtS[64];
    const int t = threadIdx.x;
    const int e0 = blockIdx.x * 32;

    // metadata: 64 threads, one per row (side). row 2e+0: self=src; row 2e+1: self=dst.
    if (t < 64) {
        int el = t >> 1, which = t & 1;
        int e = e0 + el;
        int s = src[e], d = dst[e];
        int self = which ? d : s;
        if (which == 0) { srcS[el] = s; dstS[el] = d; }
        dtS[t]  = ts[e] - last[self];
        posS[t] = atomicAdd(&cursor[self], 1);
    }
    __syncthreads();

    const int c4 = t & 31;          // float4 column within a 128-float row
    const int rg = t >> 5;          // group 0..15
    // mem gather: 64 node-rows (32 edges x {src,dst}), each written to BOTH x-rows
    #pragma unroll
    for (int i = 0; i < 4; ++i) {
        int nr = rg + i * 16;       // 0..63
        int el = nr >> 1, which = nr & 1;       // which: 0=src row, 1=dst row
        int node = which ? dstS[el] : srcS[el];
        float4 v = *(const float4*)&mem[(size_t)node * MD + c4 * 4];
        uint2 b = make_uint2(pk2bf(v.x, v.y), pk2bf(v.z, v.w));
        int rA = 2 * el, rB = 2 * el + 1;
        int swA = (rA & 7) << 3, swB = (rB & 7) << 3;
        int c16 = c4 * 4;
        if (which == 0) {           // src memory: self for row A (k=128), other for row B (k=0)
            *(uint2*)&As[rA * KX + ((128 + c16) ^ swA)] = b;
            *(uint2*)&As[rB * KX + ((0   + c16) ^ swB)] = b;
        } else {                    // dst memory: other for row A (k=0), self for row B (k=128)
            *(uint2*)&As[rA * KX + ((0   + c16) ^ swA)] = b;
            *(uint2*)&As[rB * KX + ((128 + c16) ^ swB)] = b;
        }
    }
    // edge feats: k = 356..483, written to both rows
    #pragma unroll
    for (int i = 0; i < 2; ++i) {
        int el = rg + i * 16;       // 0..31
        float4 v = *(const float4*)&ef[(size_t)(e0 + el) * EDIM + c4 * 4];
        uint2 b = make_uint2(pk2bf(v.x, v.y), pk2bf(v.z, v.w));
        int k = 356 + c4 * 4;       // %8 in {4,0}: stays inside one 8-short granule
        int rA = 2 * el, rB = 2 * el + 1;
        *(uint2*)&As[rA * KX + (k ^ ((rA & 7) << 3))] = b;
        *(uint2*)&As[rB * KX + (k ^ ((rB & 7) << 3))] = b;
    }
    // time encoding: k = 256..355 (per-row dt); 8 j-groups of 13
    {
        int s = t & 63, jg = t >> 6;
        float dt = dtS[s];
        int sw = (s & 7) << 3;
        int j1 = min(jg * 13 + 13, TD);
        for (int j = jg * 13; j < j1; ++j) {
            float v = __cosf(fmaf(dt, bfq[j], ph[j]));
            As[s * KX + ((256 + j) ^ sw)] = f2bf(v);
        }
    }
    // zero pad: k = 484..511 (64 rows x 7 short4)
    if (t < 448) {
        int s = t / 7, p = t % 7;
        int sw = (s & 7) << 3;
        int k = 484 + p * 4;
        *(short4*)&As[s * KX + (k ^ sw)] = make_short4(0, 0, 0, 0);
    }
    __syncthreads();

    const int w = t >> 6, l = t & 63, lc = l & 15, lq = l >> 4;
    f32x4 acc[4][2];                 // [row-tile][f]
    #pragma unroll
    for (int i = 0; i < 4; ++i)
        #pragma unroll
        for (int j = 0; j < 2; ++j) acc[i][j] = (f32x4){0.f, 0.f, 0.f, 0.f};

    const int rsw = (lc & 7) << 3;
    for (int ks = 0; ks < 16; ++ks) {
        bf16x8 a[4];
        #pragma unroll
        for (int rt = 0; rt < 4; ++rt)
            a[rt] = *(const bf16x8*)&As[(rt * 16 + lc) * KX + ((ks * 32 + (lq << 3)) ^ rsw)];
        #pragma unroll
        for (int f = 0; f < 2; ++f) {
            bf16x8 b = *(const bf16x8*)(Bp + (size_t)(ks * 16 + w * 2 + f) * 512 + l * 8);
            #pragma unroll
            for (int rt = 0; rt < 4; ++rt)
                acc[rt][f] = mfma16(a[rt], b, acc[rt][f]);
        }
    }

    float bb[2];
    #pragma unroll
    for (int f = 0; f < 2; ++f) bb[f] = bmsg[w * 32 + f * 16 + lc];
    #pragma unroll
    for (int rt = 0; rt < 4; ++rt) {
        #pragma unroll
        for (int jj = 0; jj < 4; ++jj) {
            int srow = rt * 16 + lq * 4 + jj;
            unsigned short* orow = msgbuf + (size_t)posS[srow] * MSGD;
            #pragma unroll
            for (int f = 0; f < 2; ++f) {
                int c = w * 32 + f * 16 + lc;
                float v = fmaxf(acc[rt][f][jj] + bb[f], 0.f);
                orow[c] = (unsigned short)f2bf(v);
            }
        }
    }
}

// GRU: 64 consecutive updated nodes/block, 512 threads (8 waves), single-phase (48 KiB LDS).
// mem staging FIRST, one barrier, full K=384 MFMA; epilogue: mv register-staged,
// f32 LDS transpose, coalesced float4 row stores (verified r14).
__global__ __launch_bounds__(512) void k_gru(const int* __restrict__ updlist, const int* __restrict__ segstart,
                                             const int* __restrict__ cntlist, const int* __restrict__ numupd,
                                             const unsigned short* __restrict__ msgbuf,
                                             const float* __restrict__ mem,
                                             const short* __restrict__ Bg, const short* __restrict__ Bh,
                                             const float* __restrict__ bih, const float* __restrict__ bhh,
                                             float* __restrict__ outmem) {
    __shared__ short Ag[GBLK * KG];                    // 48 KiB; epilogue overlays f32[64][128] on first 32 KiB
    __shared__ int sb[GBLK + 1];
    __shared__ int nodesh[GBLK];
    __shared__ float invh[GBLK];
    const int nu = *numupd;
    const int slot0 = blockIdx.x * GBLK;
    if (slot0 >= nu) return;
    const int t = threadIdx.x;
    if (t < GBLK + 1) sb[t] = segstart[min(slot0 + t, nu)];
    if (t < GBLK) {
        int slot = slot0 + t;
        if (slot < nu) { nodesh[t] = updlist[slot]; invh[t] = 1.f / (float)cntlist[slot]; }
        else           { nodesh[t] = -1;            invh[t] = 0.f; }
    }
    __syncthreads();

    // mem rows -> Ag[s][256..384)   (issued first: overlaps the seg-sum stream below)
    {
        const int c4 = t & 31, rg = t >> 5;
        #pragma unroll
        for (int i = 0; i < 4; ++i) {
            int s = rg + i * 16;
            int node = nodesh[s];
            float4 v = make_float4(0.f, 0.f, 0.f, 0.f);
            if (node >= 0) v = *(const float4*)&mem[(size_t)node * MD + c4 * 4];
            int sw = (s & 7) << 3;
            *(uint2*)&Ag[s * KG + ((256 + c4 * 4) ^ sw)] =
                make_uint2(pk2bf(v.x, v.y), pk2bf(v.z, v.w));
        }
    }
    // f32 register segment-sum: 8 threads per slot, 32 cols each (contiguous span reads)
    {
        const int g = t >> 3, q = t & 7;
        float acc[32];
        #pragma unroll
        for (int m = 0; m < 32; ++m) acc[m] = 0.f;
        const int j0 = sb[g], j1 = sb[g + 1];
        for (int j = j0; j < j1; ++j) {
            const unsigned short* rp = msgbuf + (size_t)j * MSGD + q * 32;
            #pragma unroll
            for (int h = 0; h < 4; ++h) {
                uint4 u = *(const uint4*)(rp + h * 8);
                acc[h*8+0] += bflo(u.x); acc[h*8+1] += bfhi(u.x);
                acc[h*8+2] += bflo(u.y); acc[h*8+3] += bfhi(u.y);
                acc[h*8+4] += bflo(u.z); acc[h*8+5] += bfhi(u.z);
                acc[h*8+6] += bflo(u.w); acc[h*8+7] += bfhi(u.w);
            }
        }
        const float inv = invh[g];
        const int sw = (g & 7) << 3;
        #pragma unroll
        for (int h = 0; h < 4; ++h) {
            uint4 o;
            o.x = pk2bf(acc[h*8+0] * inv, acc[h*8+1] * inv);
            o.y = pk2bf(acc[h*8+2] * inv, acc[h*8+3] * inv);
            o.z = pk2bf(acc[h*8+4] * inv, acc[h*8+5] * inv);
            o.w = pk2bf(acc[h*8+6] * inv, acc[h*8+7] * inv);
            *(uint4*)&Ag[g * KG + ((q * 32 + h * 8) ^ sw)] = o;
        }
    }
    __syncthreads();

    // MFMA: wave w -> gate col group nf = g*8+w (g<3), H col group nf = w; all 4 row-tiles.
    const int w = t >> 6, l = t & 63, lc = l & 15, lq = l >> 4;
    f32x4 accS[4][3], accH[4];
    #pragma unroll
    for (int rt = 0; rt < 4; ++rt) {
        #pragma unroll
        for (int g = 0; g < 3; ++g) accS[rt][g] = (f32x4){0.f, 0.f, 0.f, 0.f};
        accH[rt] = (f32x4){0.f, 0.f, 0.f, 0.f};
    }

    const int rsw = (lc & 7) << 3;
    for (int ks = 0; ks < 12; ++ks) {
        bf16x8 a[4];
        #pragma unroll
        for (int rt = 0; rt < 4; ++rt)
            a[rt] = *(const bf16x8*)&Ag[(rt * 16 + lc) * KG + ((ks * 32 + (lq << 3)) ^ rsw)];
        #pragma unroll
        for (int g = 0; g < 3; ++g) {
            bf16x8 b = *(const bf16x8*)(Bg + (size_t)(ks * 24 + g * 8 + w) * 512 + l * 8);
            #pragma unroll
            for (int rt = 0; rt < 4; ++rt)
                accS[rt][g] = mfma16(a[rt], b, accS[rt][g]);
        }
        if (ks >= 8) {
            bf16x8 b = *(const bf16x8*)(Bh + (size_t)((ks - 8) * 8 + w) * 512 + l * 8);
            #pragma unroll
            for (int rt = 0; rt < 4; ++rt)
                accH[rt] = mfma16(a[rt], b, accH[rt]);
        }
    }

    // register-stage mv (reads of Ag mem region) BEFORE any overlay write
    float mvr[4][4];
    {
        int d = w * 16 + lc;
        #pragma unroll
        for (int rt = 0; rt < 4; ++rt)
            #pragma unroll
            for (int jj = 0; jj < 4; ++jj) {
                int srow = rt * 16 + lq * 4 + jj;
                int sw = (srow & 7) << 3;
                mvr[rt][jj] = bf2f((unsigned short)Ag[srow * KG + ((256 + d) ^ sw)]);
            }
    }
    __syncthreads();                                   // ALL reads of Ag complete

    // epilogue: compute gate math, write f32 outputs to overlay (first 32 KiB of Ag)
    {
        float* O = (float*)Ag;
        int d = w * 16 + lc;
        float br  = bih[d] + bhh[d];
        float bz  = bih[MD + d] + bhh[MD + d];
        float bin = bih[2 * MD + d];
        float bhn = bhh[2 * MD + d];
        #pragma unroll
        for (int rt = 0; rt < 4; ++rt) {
            #pragma unroll
            for (int jj = 0; jj < 4; ++jj) {
                int srow = rt * 16 + lq * 4 + jj;
                float S_r = accS[rt][0][jj] + br;
                float S_z = accS[rt][1][jj] + bz;
                float hn  = accH[rt][jj] + bhn;
                float in_ = accS[rt][2][jj] - accH[rt][jj] + bin;
                float rr = 1.f / (1.f + __expf(-S_r));
                float zz = 1.f / (1.f + __expf(-S_z));
                float x  = fminf(fmaxf(in_ + rr * hn, -15.f), 15.f);
                float ex = __expf(-2.f * x);
                float nn = (1.f - ex) / (1.f + ex);
                float outv = (1.f - zz) * nn + zz * mvr[rt][jj];
                O[srow * 128 + (d ^ ((srow & 7) << 2))] = outv;
            }
        }
    }
    __syncthreads();

    // coalesced store: 8 threads/row, 4 float4 each
    {
        const float* O = (const float*)Ag;
        int row = t >> 3, q = t & 7;
        int node = nodesh[row];
        if (node >= 0) {
            float* orow = outmem + (size_t)node * MD;
            int sw2 = (row & 7) << 2;
            #pragma unroll
            for (int i = 0; i < 4; ++i) {
                int c0 = (q * 4 + i) * 4;
                float4 v = *(const float4*)&O[row * 128 + (c0 ^ sw2)];
                *(float4*)&orow[c0] = v;
            }
        }
    }
}

extern "C" void kernel_launch(void* const* d_in, const int* in_sizes, int n_in,
                              void* d_out, int out_size, void* d_ws, size_t ws_size,
                              hipStream_t stream) {
    const int*   src  = (const int*)d_in[0];
    const int*   dst  = (const int*)d_in[1];
    const float* ts   = (const float*)d_in[2];
    const float* ef   = (const float*)d_in[3];
    const float* mem  = (const float*)d_in[4];
    const float* last = (const float*)d_in[5];
    const float* bfq  = (const float*)d_in[6];
    const float* ph   = (const float*)d_in[7];
    const float* wmsg = (const float*)d_in[8];
    const float* bmsg = (const float*)d_in[9];
    const float* wih  = (const float*)d_in[10];
    const float* whh  = (const float*)d_in[11];
    const float* bih  = (const float*)d_in[12];
    const float* bhh  = (const float*)d_in[13];
    float* out = (float*)d_out;
    char* ws = (char*)d_ws;

    if (ws_size < WS_NEEDED) return;

    int* counts   = (int*)(ws + O_COUNTS);     // -> cursor after k_scan3
    int* numupd   = (int*)(ws + O_NUMUPD);
    int* bsumC    = (int*)(ws + O_BSUMC);
    int* bsumF    = (int*)(ws + O_BSUMF);
    int* updlist  = (int*)(ws + O_UPDLIST);
    int* segstart = (int*)(ws + O_SEGSTART);
    int* cntlist  = (int*)(ws + O_CNTLIST);
    short* bmsgp  = (short*)(ws + O_BMSG);
    short* bgp    = (short*)(ws + O_BG);
    short* bhp    = (short*)(ws + O_BH);
    unsigned short* msgbuf = (unsigned short*)(ws + O_MSGBUF);
    unsigned char*  updflag = (unsigned char*)(ws + O_UPDFLAG);
    float* out_ts = out + (size_t)NNODES * MD;

    hipMemsetAsync(ws + O_COUNTS, 0, 800004, stream);   // counts + numupd

    k_copy_ts<<<(NNODES / 4 + 255) / 256, 256, 0, stream>>>(last, out_ts);
    k_pack <<<1152, 256, 0, stream>>>(wmsg, wih, whh, bmsgp, bgp, bhp);
    k_edges<<<EDGES / 256, 256, 0, stream>>>(src, dst, ts, counts, out_ts);
    k_scan1<<<NSCAN, 256, 0, stream>>>(counts, bsumC, bsumF);
    k_scan2<<<1, 1024, 0, stream>>>(bsumC, bsumF, numupd);
    k_scan3<<<NSCAN, 256, 0, stream>>>(counts, bsumC, bsumF, updlist, segstart, cntlist, numupd, updflag);
    k_copy_mem<<<(NNODES * 32 + 255) / 256, 256, 0, stream>>>(mem, updflag, out);
    k_msg  <<<EDGES / 32, 512, 0, stream>>>(src, dst, ts, ef, mem, last, bfq, ph, bmsgp, bmsg, counts, msgbuf);
    k_gru  <<<NSIDES / GBLK, 512, 0, stream>>>(updlist, segstart, cntlist, numupd, msgbuf, mem, bgp, bhp, bih, bhh, out);
}

// Round 16
// 194.135 us; speedup vs baseline: 1.2497x; 1.1833x over previous
//
#include <hip/hip_runtime.h>
#include <hip/hip_bf16.h>
#include <math.h>

#define NNODES 200000
#define EDGES  65536
#define NSIDES (2*EDGES)        // 131072
#define MD 128
#define TD 100
#define EDIM 128
#define MSGD 256
#define KX 512                  // padded msg K (484 -> 512)
#define KG 384                  // gru combined K (256 agg + 128 mem)
#define NSCAN 782               // ceil(200000/256)
#define GBLK 64                 // k_gru slots per block

typedef __attribute__((ext_vector_type(8))) short bf16x8;
typedef __attribute__((ext_vector_type(4))) float f32x4;

// ---- workspace layout (bytes) ----
#define O_COUNTS    0u           // int[200000] -> becomes cursor after scan3
#define O_NUMUPD    800000u      // int
#define O_BSUMC     800004u      // int[782]
#define O_BSUMF     803132u      // int[782]
#define O_UPDLIST   806272u      // int[131073]
#define O_SEGSTART  1330592u     // int[131073]
#define O_CNTLIST   1854912u     // int[131072]
#define O_BMSG      2379200u     // short[16*16*64*8] = 262144 B
#define O_BG        2641344u     // short[12*24*64*8] = 294912 B
#define O_BH        2936256u     // short[4*8*64*8]   = 32768 B
#define O_MSGBUF    2969088u     // ushort[131072*256] = 67108864 B
#define O_UPDFLAG   (2969088u + 67108864u)   // uchar[200000]
#define WS_NEEDED   (2969088ull + 67108864ull + 200000ull)

__device__ __forceinline__ short f2bf(float v) {            // RNE f32->bf16 (verified)
    unsigned x = __float_as_uint(v);
    unsigned r = (x + 0x7fffu + ((x >> 16) & 1u)) >> 16;
    return (short)r;
}
__device__ __forceinline__ unsigned pk2bf(float a, float b) {    // lo=a, hi=b (pure bit ops, verified r11)
    unsigned xa = __float_as_uint(a);
    unsigned xb = __float_as_uint(b);
    unsigned ra = (xa + 0x7fffu + ((xa >> 16) & 1u)) >> 16;
    unsigned rb = (xb + 0x7fffu + ((xb >> 16) & 1u)) & 0xffff0000u;
    return ra | rb;
}
__device__ __forceinline__ float bflo(unsigned u) { return __uint_as_float(u << 16); }
__device__ __forceinline__ float bfhi(unsigned u) { return __uint_as_float(u & 0xffff0000u); }
__device__ __forceinline__ float bf2f(unsigned short u) {
    return __uint_as_float(((unsigned)u) << 16);
}
__device__ __forceinline__ f32x4 mfma16(bf16x8 a, bf16x8 b, f32x4 c) {
    return __builtin_amdgcn_mfma_f32_16x16x32_bf16(a, b, c, 0, 0, 0);
}

// ts copy: out_ts = last (must run before k_edges' atomicMax)
__global__ __launch_bounds__(256) void k_copy_ts(const float* __restrict__ last,
                                                 float* __restrict__ out_ts) {
    int i = blockIdx.x * 256 + threadIdx.x;
    if (i < NNODES / 4) ((float4*)out_ts)[i] = ((const float4*)last)[i];
}

// mem copy for NON-updated rows only (runs after scan3; updated rows written by k_gru)
__global__ __launch_bounds__(256) void k_copy_mem(const float* __restrict__ mem,
                                                  const unsigned char* __restrict__ updflag,
                                                  float* __restrict__ out) {
    size_t idx = (size_t)blockIdx.x * 256 + threadIdx.x;   // one float4 each
    if (idx >= (size_t)NNODES * 32) return;
    int node = (int)(idx >> 5);
    if (updflag[node]) return;
    ((float4*)out)[idx] = ((const float4*)mem)[idx];
}

// pack weights into MFMA-fragment-linear bf16
// A-frag: lane l holds A[row=l&15][k=(l>>4)*8+j]; B-frag: lane l holds B[k=(l>>4)*8+j][col=l&15]
__global__ __launch_bounds__(256) void k_pack(const float* __restrict__ wmsg,
                                              const float* __restrict__ wih,
                                              const float* __restrict__ whh,
                                              short* __restrict__ bmsgp,
                                              short* __restrict__ bgp,
                                              short* __restrict__ bhp) {
    const int NM = 16 * 16 * 64 * 8;   // K=512, N=256
    const int NG = 12 * 24 * 64 * 8;   // K=384, N=384
    const int NH = 4 * 8 * 64 * 8;     // K=128, N=128 (n-gate of W_hh)
    int idx = blockIdx.x * 256 + threadIdx.x;
    if (idx < NM) {
        int j = idx & 7, l = (idx >> 3) & 63, nf = (idx >> 9) & 15, ks = idx >> 13;
        int n = nf * 16 + (l & 15);
        int k = ks * 32 + ((l >> 4) << 3) + j;
        bmsgp[idx] = f2bf(k < 484 ? wmsg[n * 484 + k] : 0.f);
    } else if (idx < NM + NG) {
        int i = idx - NM;
        int j = i & 7, l = (i >> 3) & 63, rest = i >> 9;
        int nf = rest % 24, ks = rest / 24;
        int n = nf * 16 + (l & 15);
        int k = ks * 32 + ((l >> 4) << 3) + j;
        float v = (k < 256) ? wih[n * 256 + k] : whh[n * 128 + (k - 256)];
        bgp[i] = f2bf(v);
    } else if (idx < NM + NG + NH) {
        int i = idx - NM - NG;
        int j = i & 7, l = (i >> 3) & 63, rest = i >> 9;
        int nf = rest & 7, ks = rest >> 3;
        int n = 256 + nf * 16 + (l & 15);
        int k = ks * 32 + ((l >> 4) << 3) + j;
        bhp[i] = f2bf(whh[n * 128 + k]);
    }
}

__global__ __launch_bounds__(256) void k_edges(const int* __restrict__ src, const int* __restrict__ dst,
                                               const float* __restrict__ ts,
                                               int* __restrict__ counts, float* __restrict__ out_ts) {
    int e = blockIdx.x * blockDim.x + threadIdx.x;
    if (e >= EDGES) return;
    int s = src[e], d = dst[e];
    unsigned tb = __float_as_uint(ts[e]);   // ts >= 0 -> uint order == float order
    atomicAdd(&counts[s], 1);
    atomicAdd(&counts[d], 1);
    atomicMax((unsigned*)&out_ts[s], tb);
    atomicMax((unsigned*)&out_ts[d], tb);
}

__global__ __launch_bounds__(256) void k_scan1(const int* __restrict__ counts,
                                               int* __restrict__ bsumC, int* __restrict__ bsumF) {
    __shared__ int sC[256], sF[256];
    int t = threadIdx.x, i = blockIdx.x * 256 + t;
    int c = (i < NNODES) ? counts[i] : 0;
    sC[t] = c; sF[t] = (c > 0) ? 1 : 0;
    __syncthreads();
    for (int off = 128; off > 0; off >>= 1) {
        if (t < off) { sC[t] += sC[t + off]; sF[t] += sF[t + off]; }
        __syncthreads();
    }
    if (t == 0) { bsumC[blockIdx.x] = sC[0]; bsumF[blockIdx.x] = sF[0]; }
}

__global__ __launch_bounds__(1024) void k_scan2(int* __restrict__ bsumC, int* __restrict__ bsumF,
                                                int* __restrict__ numupd) {
    __shared__ int sC[1024], sF[1024];
    int t = threadIdx.x;
    int c = (t < NSCAN) ? bsumC[t] : 0;
    int f = (t < NSCAN) ? bsumF[t] : 0;
    sC[t] = c; sF[t] = f;
    __syncthreads();
    for (int off = 1; off < 1024; off <<= 1) {
        int vc = (t >= off) ? sC[t - off] : 0;
        int vf = (t >= off) ? sF[t - off] : 0;
        __syncthreads();
        sC[t] += vc; sF[t] += vf;
        __syncthreads();
    }
    if (t < NSCAN) { bsumC[t] = sC[t] - c; bsumF[t] = sF[t] - f; }  // exclusive
    if (t == 0) numupd[0] = sF[1023];
}

__global__ __launch_bounds__(256) void k_scan3(int* __restrict__ counts,   // in: counts, out: cursor
                                               const int* __restrict__ bsumC, const int* __restrict__ bsumF,
                                               int* __restrict__ updlist, int* __restrict__ segstart,
                                               int* __restrict__ cntlist, const int* __restrict__ numupd,
                                               unsigned char* __restrict__ updflag) {
    __shared__ int sC[256], sF[256];
    int t = threadIdx.x, b = blockIdx.x, i = b * 256 + t;
    int c = (i < NNODES) ? counts[i] : 0;
    int fl = (c > 0) ? 1 : 0;
    sC[t] = c; sF[t] = fl;
    __syncthreads();
    for (int off = 1; off < 256; off <<= 1) {
        int vc = (t >= off) ? sC[t - off] : 0;
        int vf = (t >= off) ? sF[t - off] : 0;
        __syncthreads();
        sC[t] += vc; sF[t] += vf;
        __syncthreads();
    }
    if (i < NNODES) {
        int segC = bsumC[b] + sC[t] - c;
        int rank = bsumF[b] + sF[t] - fl;
        if (fl) {
            updlist[rank]  = i;
            segstart[rank] = segC;
            cntlist[rank]  = c;
        }
        updflag[i] = (unsigned char)fl;
        counts[i] = segC;                              // becomes cursor
        if (i == NNODES - 1) segstart[numupd[0]] = segC + c;   // sentinel = 131072
    }
}

// message GEMM: 32 EDGES (64 rows) per block, 512 threads (8 waves), single-phase (64 KiB LDS).
// Each wave owns 2 nf (32 cols) over all 64 rows -> every B-frag loaded once per block.
__global__ __launch_bounds__(512) void k_msg(const int* __restrict__ src, const int* __restrict__ dst,
                                             const float* __restrict__ ts, const float* __restrict__ ef,
                                             const float* __restrict__ mem, const float* __restrict__ last,
                                             const float* __restrict__ bfq, const float* __restrict__ ph,
                                             const short* __restrict__ Bp, const float* __restrict__ bmsg,
                                             int* __restrict__ cursor, unsigned short* __restrict__ msgbuf) {
    __shared__ short As[64 * KX];                      // 64 KiB
    __shared__ int srcS[32], dstS[32], posS[64];
    __shared__ float dtS[64];
    const int t = threadIdx.x;
    const int e0 = blockIdx.x * 32;

    // metadata: 64 threads, one per row (side). row 2e+0: self=src; row 2e+1: self=dst.
    if (t < 64) {
        int el = t >> 1, which = t & 1;
        int e = e0 + el;
        int s = src[e], d = dst[e];
        int self = which ? d : s;
        if (which == 0) { srcS[el] = s; dstS[el] = d; }
        dtS[t]  = ts[e] - last[self];
        posS[t] = atomicAdd(&cursor[self], 1);
    }
    __syncthreads();

    const int c4 = t & 31;          // float4 column within a 128-float row
    const int rg = t >> 5;          // group 0..15
    // mem gather: 64 node-rows (32 edges x {src,dst}), each written to BOTH x-rows
    #pragma unroll
    for (int i = 0; i < 4; ++i) {
        int nr = rg + i * 16;       // 0..63
        int el = nr >> 1, which = nr & 1;       // which: 0=src row, 1=dst row
        int node = which ? dstS[el] : srcS[el];
        float4 v = *(const float4*)&mem[(size_t)node * MD + c4 * 4];
        uint2 b = make_uint2(pk2bf(v.x, v.y), pk2bf(v.z, v.w));
        int rA = 2 * el, rB = 2 * el + 1;
        int swA = (rA & 7) << 3, swB = (rB & 7) << 3;
        int c16 = c4 * 4;
        if (which == 0) {           // src memory: self for row A (k=128), other for row B (k=0)
            *(uint2*)&As[rA * KX + ((128 + c16) ^ swA)] = b;
            *(uint2*)&As[rB * KX + ((0   + c16) ^ swB)] = b;
        } else {                    // dst memory: other for row A (k=0), self for row B (k=128)
            *(uint2*)&As[rA * KX + ((0   + c16) ^ swA)] = b;
            *(uint2*)&As[rB * KX + ((128 + c16) ^ swB)] = b;
        }
    }
    // edge feats: k = 356..483, written to both rows
    #pragma unroll
    for (int i = 0; i < 2; ++i) {
        int el = rg + i * 16;       // 0..31
        float4 v = *(const float4*)&ef[(size_t)(e0 + el) * EDIM + c4 * 4];
        uint2 b = make_uint2(pk2bf(v.x, v.y), pk2bf(v.z, v.w));
        int k = 356 + c4 * 4;       // %8 in {4,0}: stays inside one 8-short granule
        int rA = 2 * el, rB = 2 * el + 1;
        *(uint2*)&As[rA * KX + (k ^ ((rA & 7) << 3))] = b;
        *(uint2*)&As[rB * KX + (k ^ ((rB & 7) << 3))] = b;
    }
    // time encoding: k = 256..355 (per-row dt); 8 j-groups of 13
    {
        int s = t & 63, jg = t >> 6;
        float dt = dtS[s];
        int sw = (s & 7) << 3;
        int j1 = min(jg * 13 + 13, TD);
        for (int j = jg * 13; j < j1; ++j) {
            float v = __cosf(fmaf(dt, bfq[j], ph[j]));
            As[s * KX + ((256 + j) ^ sw)] = f2bf(v);
        }
    }
    // zero pad: k = 484..511 (64 rows x 7 short4)
    if (t < 448) {
        int s = t / 7, p = t % 7;
        int sw = (s & 7) << 3;
        int k = 484 + p * 4;
        *(short4*)&As[s * KX + (k ^ sw)] = make_short4(0, 0, 0, 0);
    }
    __syncthreads();

    const int w = t >> 6, l = t & 63, lc = l & 15, lq = l >> 4;
    f32x4 acc[4][2];                 // [row-tile][f]
    #pragma unroll
    for (int i = 0; i < 4; ++i)
        #pragma unroll
        for (int j = 0; j < 2; ++j) acc[i][j] = (f32x4){0.f, 0.f, 0.f, 0.f};

    const int rsw = (lc & 7) << 3;
    for (int ks = 0; ks < 16; ++ks) {
        bf16x8 a[4];
        #pragma unroll
        for (int rt = 0; rt < 4; ++rt)
            a[rt] = *(const bf16x8*)&As[(rt * 16 + lc) * KX + ((ks * 32 + (lq << 3)) ^ rsw)];
        #pragma unroll
        for (int f = 0; f < 2; ++f) {
            bf16x8 b = *(const bf16x8*)(Bp + (size_t)(ks * 16 + w * 2 + f) * 512 + l * 8);
            #pragma unroll
            for (int rt = 0; rt < 4; ++rt)
                acc[rt][f] = mfma16(a[rt], b, acc[rt][f]);
        }
    }

    float bb[2];
    #pragma unroll
    for (int f = 0; f < 2; ++f) bb[f] = bmsg[w * 32 + f * 16 + lc];
    #pragma unroll
    for (int rt = 0; rt < 4; ++rt) {
        #pragma unroll
        for (int jj = 0; jj < 4; ++jj) {
            int srow = rt * 16 + lq * 4 + jj;
            unsigned short* orow = msgbuf + (size_t)posS[srow] * MSGD;
            #pragma unroll
            for (int f = 0; f < 2; ++f) {
                int c = w * 32 + f * 16 + lc;
                float v = fmaxf(acc[rt][f][jj] + bb[f], 0.f);
                orow[c] = (unsigned short)f2bf(v);
            }
        }
    }
}

// GRU: 64 consecutive updated nodes/block, 512 threads (8 waves), single-phase (48 KiB LDS).
// mem staging issued FIRST (overlaps the seg-sum's latency), one barrier, full K=384 MFMA.
__global__ __launch_bounds__(512) void k_gru(const int* __restrict__ updlist, const int* __restrict__ segstart,
                                             const int* __restrict__ cntlist, const int* __restrict__ numupd,
                                             const unsigned short* __restrict__ msgbuf,
                                             const float* __restrict__ mem,
                                             const short* __restrict__ Bg, const short* __restrict__ Bh,
                                             const float* __restrict__ bih, const float* __restrict__ bhh,
                                             float* __restrict__ outmem) {
    __shared__ short Ag[GBLK * KG];                    // 48 KiB
    __shared__ int sb[GBLK + 1];
    __shared__ int nodesh[GBLK];
    __shared__ float invh[GBLK];
    const int nu = *numupd;
    const int slot0 = blockIdx.x * GBLK;
    if (slot0 >= nu) return;
    const int t = threadIdx.x;
    if (t < GBLK + 1) sb[t] = segstart[min(slot0 + t, nu)];
    if (t < GBLK) {
        int slot = slot0 + t;
        if (slot < nu) { nodesh[t] = updlist[slot]; invh[t] = 1.f / (float)cntlist[slot]; }
        else           { nodesh[t] = -1;            invh[t] = 0.f; }
    }
    __syncthreads();

    // mem rows -> Ag[s][256..384)   (issued first: overlaps the seg-sum stream below)
    {
        const int c4 = t & 31, rg = t >> 5;
        #pragma unroll
        for (int i = 0; i < 4; ++i) {
            int s = rg + i * 16;
            int node = nodesh[s];
            float4 v = make_float4(0.f, 0.f, 0.f, 0.f);
            if (node >= 0) v = *(const float4*)&mem[(size_t)node * MD + c4 * 4];
            int sw = (s & 7) << 3;
            *(uint2*)&Ag[s * KG + ((256 + c4 * 4) ^ sw)] =
                make_uint2(pk2bf(v.x, v.y), pk2bf(v.z, v.w));
        }
    }
    // f32 register segment-sum: 8 threads per slot, 32 cols each (contiguous span reads)
    {
        const int g = t >> 3, q = t & 7;
        float acc[32];
        #pragma unroll
        for (int m = 0; m < 32; ++m) acc[m] = 0.f;
        const int j0 = sb[g], j1 = sb[g + 1];
        for (int j = j0; j < j1; ++j) {
            const unsigned short* rp = msgbuf + (size_t)j * MSGD + q * 32;
            #pragma unroll
            for (int h = 0; h < 4; ++h) {
                uint4 u = *(const uint4*)(rp + h * 8);
                acc[h*8+0] += bflo(u.x); acc[h*8+1] += bfhi(u.x);
                acc[h*8+2] += bflo(u.y); acc[h*8+3] += bfhi(u.y);
                acc[h*8+4] += bflo(u.z); acc[h*8+5] += bfhi(u.z);
                acc[h*8+6] += bflo(u.w); acc[h*8+7] += bfhi(u.w);
            }
        }
        const float inv = invh[g];
        const int sw = (g & 7) << 3;
        #pragma unroll
        for (int h = 0; h < 4; ++h) {
            uint4 o;
            o.x = pk2bf(acc[h*8+0] * inv, acc[h*8+1] * inv);
            o.y = pk2bf(acc[h*8+2] * inv, acc[h*8+3] * inv);
            o.z = pk2bf(acc[h*8+4] * inv, acc[h*8+5] * inv);
            o.w = pk2bf(acc[h*8+6] * inv, acc[h*8+7] * inv);
            *(uint4*)&Ag[g * KG + ((q * 32 + h * 8) ^ sw)] = o;
        }
    }
    __syncthreads();

    // MFMA: wave w -> gate col group nf = g*8+w (g<3), H col group nf = w; all 4 row-tiles.
    const int w = t >> 6, l = t & 63, lc = l & 15, lq = l >> 4;
    f32x4 accS[4][3], accH[4];
    #pragma unroll
    for (int rt = 0; rt < 4; ++rt) {
        #pragma unroll
        for (int g = 0; g < 3; ++g) accS[rt][g] = (f32x4){0.f, 0.f, 0.f, 0.f};
        accH[rt] = (f32x4){0.f, 0.f, 0.f, 0.f};
    }

    const int rsw = (lc & 7) << 3;
    for (int ks = 0; ks < 12; ++ks) {
        bf16x8 a[4];
        #pragma unroll
        for (int rt = 0; rt < 4; ++rt)
            a[rt] = *(const bf16x8*)&Ag[(rt * 16 + lc) * KG + ((ks * 32 + (lq << 3)) ^ rsw)];
        #pragma unroll
        for (int g = 0; g < 3; ++g) {
            bf16x8 b = *(const bf16x8*)(Bg + (size_t)(ks * 24 + g * 8 + w) * 512 + l * 8);
            #pragma unroll
            for (int rt = 0; rt < 4; ++rt)
                accS[rt][g] = mfma16(a[rt], b, accS[rt][g]);
        }
        if (ks >= 8) {
            bf16x8 b = *(const bf16x8*)(Bh + (size_t)((ks - 8) * 8 + w) * 512 + l * 8);
            #pragma unroll
            for (int rt = 0; rt < 4; ++rt)
                accH[rt] = mfma16(a[rt], b, accH[rt]);
        }
    }

    {
        int d = w * 16 + lc;
        float br  = bih[d] + bhh[d];
        float bz  = bih[MD + d] + bhh[MD + d];
        float bin = bih[2 * MD + d];
        float bhn = bhh[2 * MD + d];
        #pragma unroll
        for (int rt = 0; rt < 4; ++rt) {
            #pragma unroll
            for (int jj = 0; jj < 4; ++jj) {
                int srow = rt * 16 + lq * 4 + jj;
                int node = nodesh[srow];
                if (node < 0) continue;
                float S_r = accS[rt][0][jj] + br;
                float S_z = accS[rt][1][jj] + bz;
                float hn  = accH[rt][jj] + bhn;
                float in_ = accS[rt][2][jj] - accH[rt][jj] + bin;
                float rr = 1.f / (1.f + __expf(-S_r));
                float zz = 1.f / (1.f + __expf(-S_z));
                float x  = fminf(fmaxf(in_ + rr * hn, -15.f), 15.f);
                float ex = __expf(-2.f * x);
                float nn = (1.f - ex) / (1.f + ex);
                int sw = (srow & 7) << 3;
                float mv = bf2f((unsigned short)Ag[srow * KG + ((256 + d) ^ sw)]);
                outmem[(size_t)node * MD + d] = (1.f - zz) * nn + zz * mv;
            }
        }
    }
}

extern "C" void kernel_launch(void* const* d_in, const int* in_sizes, int n_in,
                              void* d_out, int out_size, void* d_ws, size_t ws_size,
                              hipStream_t stream) {
    const int*   src  = (const int*)d_in[0];
    const int*   dst  = (const int*)d_in[1];
    const float* ts   = (const float*)d_in[2];
    const float* ef   = (const float*)d_in[3];
    const float* mem  = (const float*)d_in[4];
    const float* last = (const float*)d_in[5];
    const float* bfq  = (const float*)d_in[6];
    const float* ph   = (const float*)d_in[7];
    const float* wmsg = (const float*)d_in[8];
    const float* bmsg = (const float*)d_in[9];
    const float* wih  = (const float*)d_in[10];
    const float* whh  = (const float*)d_in[11];
    const float* bih  = (const float*)d_in[12];
    const float* bhh  = (const float*)d_in[13];
    float* out = (float*)d_out;
    char* ws = (char*)d_ws;

    if (ws_size < WS_NEEDED) return;

    int* counts   = (int*)(ws + O_COUNTS);     // -> cursor after k_scan3
    int* numupd   = (int*)(ws + O_NUMUPD);
    int* bsumC    = (int*)(ws + O_BSUMC);
    int* bsumF    = (int*)(ws + O_BSUMF);
    int* updlist  = (int*)(ws + O_UPDLIST);
    int* segstart = (int*)(ws + O_SEGSTART);
    int* cntlist  = (int*)(ws + O_CNTLIST);
    short* bmsgp  = (short*)(ws + O_BMSG);
    short* bgp    = (short*)(ws + O_BG);
    short* bhp    = (short*)(ws + O_BH);
    unsigned short* msgbuf = (unsigned short*)(ws + O_MSGBUF);
    unsigned char*  updflag = (unsigned char*)(ws + O_UPDFLAG);
    float* out_ts = out + (size_t)NNODES * MD;

    hipMemsetAsync(ws + O_COUNTS, 0, 800004, stream);   // counts + numupd

    k_copy_ts<<<(NNODES / 4 + 255) / 256, 256, 0, stream>>>(last, out_ts);
    k_pack <<<1152, 256, 0, stream>>>(wmsg, wih, whh, bmsgp, bgp, bhp);
    k_edges<<<EDGES / 256, 256, 0, stream>>>(src, dst, ts, counts, out_ts);
    k_scan1<<<NSCAN, 256, 0, stream>>>(counts, bsumC, bsumF);
    k_scan2<<<1, 1024, 0, stream>>>(bsumC, bsumF, numupd);
    k_scan3<<<NSCAN, 256, 0, stream>>>(counts, bsumC, bsumF, updlist, segstart, cntlist, numupd, updflag);
    k_copy_mem<<<(NNODES * 32 + 255) / 256, 256, 0, stream>>>(mem, updflag, out);
    k_msg  <<<EDGES / 32, 512, 0, stream>>>(src, dst, ts, ef, mem, last, bfq, ph, bmsgp, bmsg, counts, msgbuf);
    k_gru  <<<NSIDES / GBLK, 512, 0, stream>>>(updlist, segstart, cntlist, numupd, msgbuf, mem, bgp, bhp, bih, bhh, out);
}